// Round 2
// baseline (127.197 us; speedup 1.0000x reference)
//
#include <hip/hip_runtime.h>
#include <hip/hip_bf16.h>
#include <math.h>

// Problem constants
#define B_   16
#define HID_ 1024
#define LH_  32
#define LD_  128
#define BLOCK_ 16
#define NBPS_  64
#define MAXLEN_ 1024
#define SPLIT_ 8
#define CHUNK_ (MAXLEN_ / SPLIT_)   // 128

// ---------------- q projection: q[b][j] = sum_k hs[b][k] * qw[j][k] ----------
__global__ __launch_bounds__(256) void qproj_kernel(const float* __restrict__ hs,
                                                    const float* __restrict__ w,
                                                    float* __restrict__ q) {
    int t = threadIdx.x;
    int row0 = blockIdx.x * 4;          // 4096/4 = 1024 blocks
    float wr[4][4];
#pragma unroll
    for (int r = 0; r < 4; ++r)
#pragma unroll
        for (int s = 0; s < 4; ++s)
            wr[r][s] = w[(size_t)(row0 + r) * HID_ + t + 256 * s];

    __shared__ float lds[4][4];
    for (int b = 0; b < B_; ++b) {
        float a[4];
#pragma unroll
        for (int s = 0; s < 4; ++s) a[s] = hs[b * HID_ + t + 256 * s];
        float p[4];
#pragma unroll
        for (int r = 0; r < 4; ++r)
            p[r] = wr[r][0]*a[0] + wr[r][1]*a[1] + wr[r][2]*a[2] + wr[r][3]*a[3];
#pragma unroll
        for (int off = 32; off; off >>= 1)
#pragma unroll
            for (int r = 0; r < 4; ++r) p[r] += __shfl_xor(p[r], off);
        int lane = t & 63, wv = t >> 6;
        if (lane == 0)
#pragma unroll
            for (int r = 0; r < 4; ++r) lds[wv][r] = p[r];
        __syncthreads();
        if (t < 4)
            q[b * 4096 + row0 + t] = lds[0][t] + lds[1][t] + lds[2][t] + lds[3][t];
        __syncthreads();
    }
}

// ---------------- RoPE (in-place on q_ws), folds 1/sqrt(LD) scale -----------
// Double precision throughout: tiny kernel, and fp32 phase error (pos up to
// ~1029 rad) otherwise dominates the end-to-end error budget.
__global__ __launch_bounds__(256) void rope_kernel(float* __restrict__ q,
                                                   const int* __restrict__ pos_ids,
                                                   const int* __restrict__ nspec) {
    int idx = blockIdx.x * 256 + threadIdx.x;   // 16*32*64 = 32768 total
    int b = idx >> 11;
    int rem = idx & 2047;
    int h = rem >> 6;
    int d = rem & 63;
    double pos = (double)(pos_ids[b] + nspec[0]);
    double inv_freq = 1.0 / pow(10000.0, (double)d * (1.0 / 64.0));
    double f = pos * inv_freq;
    double cs = cos(f), sn = sin(f);
    int base = b * 4096 + h * LD_ + d;
    double x0 = (double)q[base], x1 = (double)q[base + 64];
    const double scale = 0.08838834764831845;   // 1/sqrt(128)
    q[base]      = (float)((x0 * cs - x1 * sn) * scale);
    q[base + 64] = (float)((x1 * cs + x0 * sn) * scale);
}

// ---------------- flash-decode attention partials ---------------------------
__global__ __launch_bounds__(256) void attn_kernel(const float* __restrict__ q,
                                                   const float* __restrict__ kc,
                                                   const float* __restrict__ vc,
                                                   const int* __restrict__ btab,
                                                   const int* __restrict__ slen,
                                                   float* __restrict__ pml,
                                                   float* __restrict__ pacc) {
    int c = blockIdx.x, h = blockIdx.y, b = blockIdx.z;
    int L = slen[b];
    int start = c * CHUNK_;
    int bh = b * LH_ + h;
    int pbase = bh * SPLIT_ + c;
    int t = threadIdx.x;

    if (start >= L) {
        if (t < 128) pacc[(size_t)pbase * 128 + t] = 0.f;
        if (t == 0) { pml[pbase * 2] = -INFINITY; pml[pbase * 2 + 1] = 0.f; }
        return;
    }

    int lane = t & 63, wv = t >> 6;
    int lg = lane & 15;
    int d0 = lg * 8;
    const float* qp = q + (size_t)bh * LD_ + d0;
    float4 qa = *(const float4*)qp;
    float4 qb = *(const float4*)(qp + 4);

    int end = min(start + CHUNK_, L);
    float m = -INFINITY, l = 0.f;
    float acc[8];
#pragma unroll
    for (int k = 0; k < 8; ++k) acc[k] = 0.f;

    for (int pos = start + wv * 4 + (lane >> 4); pos < end; pos += 16) {
        int blk = btab[b * NBPS_ + (pos >> 4)];
        size_t off = (((size_t)blk * LH_ + h) * BLOCK_ + (pos & 15)) * LD_ + d0;
        float4 k0 = *(const float4*)(kc + off);
        float4 k1 = *(const float4*)(kc + off + 4);
        float4 v0 = *(const float4*)(vc + off);
        float4 v1 = *(const float4*)(vc + off + 4);

        float dot = qa.x*k0.x + qa.y*k0.y + qa.z*k0.z + qa.w*k0.w
                  + qb.x*k1.x + qb.y*k1.y + qb.z*k1.z + qb.w*k1.w;
#pragma unroll
        for (int o = 1; o < 16; o <<= 1) dot += __shfl_xor(dot, o);

        float mn = fmaxf(m, dot);
        float r = (m >= mn) ? 1.f : expf(m - mn);
        float p = expf(dot - mn);
        l = l * r + p;
        acc[0] = acc[0]*r + p*v0.x;  acc[1] = acc[1]*r + p*v0.y;
        acc[2] = acc[2]*r + p*v0.z;  acc[3] = acc[3]*r + p*v0.w;
        acc[4] = acc[4]*r + p*v1.x;  acc[5] = acc[5]*r + p*v1.y;
        acc[6] = acc[6]*r + p*v1.z;  acc[7] = acc[7]*r + p*v1.w;
        m = mn;
    }

    // merge the 4 16-lane groups within the wave
#pragma unroll
    for (int o = 16; o < 64; o <<= 1) {
        float m2 = __shfl_xor(m, o), l2 = __shfl_xor(l, o);
        float a2[8];
#pragma unroll
        for (int k = 0; k < 8; ++k) a2[k] = __shfl_xor(acc[k], o);
        float mn = fmaxf(m, m2);
        float ra = (m  >= mn) ? 1.f : expf(m  - mn);
        float rb = (m2 >= mn) ? 1.f : expf(m2 - mn);
        l = l * ra + l2 * rb;
#pragma unroll
        for (int k = 0; k < 8; ++k) acc[k] = acc[k]*ra + a2[k]*rb;
        m = mn;
    }

    __shared__ float sm[4], sl[4], sacc[4][128];
    if (lane < 16) {
#pragma unroll
        for (int k = 0; k < 8; ++k) sacc[wv][d0 + k] = acc[k];
        if (lane == 0) { sm[wv] = m; sl[wv] = l; }
    }
    __syncthreads();

    if (t < 64) {
        float M = fmaxf(fmaxf(sm[0], sm[1]), fmaxf(sm[2], sm[3]));
        int d = t * 2;
        float lt = 0.f, o0 = 0.f, o1 = 0.f;
#pragma unroll
        for (int w2 = 0; w2 < 4; ++w2) {
            float mw = sm[w2];
            float e = (mw >= M) ? 1.f : expf(mw - M);
            lt += e * sl[w2];
            o0 += e * sacc[w2][d];
            o1 += e * sacc[w2][d + 1];
        }
        pacc[(size_t)pbase * 128 + d]     = o0;
        pacc[(size_t)pbase * 128 + d + 1] = o1;
        if (t == 0) { pml[pbase * 2] = M; pml[pbase * 2 + 1] = lt; }
    }
}

// ---------------- combine chunk partials ------------------------------------
__global__ __launch_bounds__(64) void combine_kernel(const float* __restrict__ pml,
                                                     const float* __restrict__ pacc,
                                                     float* __restrict__ attn) {
    int bh = blockIdx.x;
    int lane = threadIdx.x;
    float M = -INFINITY;
#pragma unroll
    for (int c = 0; c < SPLIT_; ++c) M = fmaxf(M, pml[(bh * SPLIT_ + c) * 2]);
    int d = lane * 2;
    float lt = 0.f, o0 = 0.f, o1 = 0.f;
#pragma unroll
    for (int c = 0; c < SPLIT_; ++c) {
        float mc = pml[(bh * SPLIT_ + c) * 2];
        float e = (mc >= M) ? 1.f : expf(mc - M);
        lt += e * pml[(bh * SPLIT_ + c) * 2 + 1];
        o0 += e * pacc[((size_t)bh * SPLIT_ + c) * 128 + d];
        o1 += e * pacc[((size_t)bh * SPLIT_ + c) * 128 + d + 1];
    }
    float inv = 1.f / lt;
    attn[(size_t)bh * LD_ + d]     = o0 * inv;
    attn[(size_t)bh * LD_ + d + 1] = o1 * inv;
}

// ---------------- o projection: out[b][i] = sum_j attn[b][j]*ow[i][j] -------
__global__ __launch_bounds__(256) void oproj_kernel(const float* __restrict__ attn,
                                                    const float* __restrict__ w,
                                                    float* __restrict__ out) {
    int t = threadIdx.x;
    int row0 = blockIdx.x * 4;          // 1024/4 = 256 blocks
    float wr[4][16];
#pragma unroll
    for (int r = 0; r < 4; ++r)
#pragma unroll
        for (int s = 0; s < 16; ++s)
            wr[r][s] = w[(size_t)(row0 + r) * 4096 + t + 256 * s];

    __shared__ float lds[4][4];
    for (int b = 0; b < B_; ++b) {
        float p[4] = {0.f, 0.f, 0.f, 0.f};
#pragma unroll
        for (int s = 0; s < 16; ++s) {
            float a = attn[b * 4096 + t + 256 * s];
#pragma unroll
            for (int r = 0; r < 4; ++r) p[r] += wr[r][s] * a;
        }
#pragma unroll
        for (int off = 32; off; off >>= 1)
#pragma unroll
            for (int r = 0; r < 4; ++r) p[r] += __shfl_xor(p[r], off);
        int lane = t & 63, wv = t >> 6;
        if (lane == 0)
#pragma unroll
            for (int r = 0; r < 4; ++r) lds[wv][r] = p[r];
        __syncthreads();
        if (t < 4)
            out[b * HID_ + row0 + t] = lds[0][t] + lds[1][t] + lds[2][t] + lds[3][t];
        __syncthreads();
    }
}

extern "C" void kernel_launch(void* const* d_in, const int* in_sizes, int n_in,
                              void* d_out, int out_size, void* d_ws, size_t ws_size,
                              hipStream_t stream) {
    const float* hs   = (const float*)d_in[0];
    const float* qw   = (const float*)d_in[1];
    const float* ow   = (const float*)d_in[2];
    const float* kc   = (const float*)d_in[3];
    const float* vc   = (const float*)d_in[4];
    const int*   btab = (const int*)d_in[5];
    const int*   slen = (const int*)d_in[6];
    const int*   pid  = (const int*)d_in[7];
    const int*   nsp  = (const int*)d_in[8];
    float* out = (float*)d_out;
    float* ws  = (float*)d_ws;

    float* q_ws    = ws;            // 65536 floats
    float* attn_ws = ws + 65536;    // 65536 floats
    float* pml     = ws + 131072;   // 8192 floats
    float* pacc    = ws + 139264;   // 524288 floats

    qproj_kernel<<<1024, 256, 0, stream>>>(hs, qw, q_ws);
    rope_kernel<<<128, 256, 0, stream>>>(q_ws, pid, nsp);
    attn_kernel<<<dim3(SPLIT_, LH_, B_), 256, 0, stream>>>(q_ws, kc, vc, btab, slen, pml, pacc);
    combine_kernel<<<B_ * LH_, 64, 0, stream>>>(pml, pacc, attn_ws);
    oproj_kernel<<<256, 256, 0, stream>>>(attn_ws, ow, out);
}